// Round 1
// baseline (136.608 us; speedup 1.0000x reference)
//
#include <hip/hip_runtime.h>
#include <math.h>

// TransformDomainInterpolator — split-kernel version.
//
// K1 (tdi_fft): one (batch,symbol) per 256-thread block, grid = 2*batch.
//   Same verified register-radix-8 FFT math as the 131.7µs kernel
//   (fwd 2048-pt, pointwise half-shift filter, inv 2048-pt), but:
//     - 6 LDS phases instead of 7 (final inverse stage stores odd-interp
//       REAL parts straight from registers to workspace; no LDS round-trip)
//     - 4 independent blocks/CU instead of 2 -> barrier-stall overlap
//   ws[b*4096 + sym*2048 + n] = Re(odd_interp[n])
//
// K2 (tdi_lerp): pure streaming epilogue, grid = 4*batch x 256 thr.
//   out[b,t,4q..4q+3] = [lerp(even 2q), lerp(odd 2q), lerp(even 2q+1),
//   lerp(odd 2q+1)], w = [0,0, 0/9..8/9, 1,1,1]; float4 stores,
//   write-BW-bound (117 MB).
//
// Math (verified R3/R4 of previous session, absmax 0.0156):
//   even[m] = in_r[b, s*2048+m] (exact)
//   odd = IDFT_2048( t_k * DFT_2048(x_s) )/2048, t_k = ±e^{i pi k/2048}

#define NSC  4096
#define PI_F 3.14159265358979323846f
#define RSQ2 0.70710678118654752f

__device__ __forceinline__ int pada(int i) { return i + 2 * (i >> 5); }

__device__ __forceinline__ void bf_fwd(float2& a, float2& c, float tc, float ts) {
  const float tx = a.x - c.x, ty = a.y - c.y;
  a.x += c.x; a.y += c.y;
  c.x = tx * tc - ty * ts;
  c.y = tx * ts + ty * tc;
}
__device__ __forceinline__ void bf_inv(float2& a, float2& c, float tc, float ts) {
  const float tx = c.x * tc - c.y * ts, ty = c.x * ts + c.y * tc;
  c.x = a.x - tx; c.y = a.y - ty;
  a.x += tx; a.y += ty;
}

// Forward 3-stage block: pairs (j,j+4) tw e^{-i(th+j pi/4)}; (j,j+2) tw
// e^{-i 2th} / e^{-i(2th+pi/2)}; (j,j+1) tw e^{-i 4th}.  (c,s)=sincos(th).
__device__ __forceinline__ void fwd3(float2* x, float c, float s) {
  bf_fwd(x[0], x[4], c, -s);
  { const float cj = RSQ2 * (c - s), sj = RSQ2 * (c + s);
    bf_fwd(x[1], x[5], cj, -sj); }
  bf_fwd(x[2], x[6], -s, -c);
  { const float cj = -RSQ2 * (s + c), sj = RSQ2 * (c - s);
    bf_fwd(x[3], x[7], cj, -sj); }
  const float c2 = c * c - s * s, s2 = 2.f * c * s;
  bf_fwd(x[0], x[2], c2, -s2);  bf_fwd(x[4], x[6], c2, -s2);
  bf_fwd(x[1], x[3], -s2, -c2); bf_fwd(x[5], x[7], -s2, -c2);
  const float c4 = c2 * c2 - s2 * s2, s4 = 2.f * c2 * s2;
  bf_fwd(x[0], x[1], c4, -s4); bf_fwd(x[2], x[3], c4, -s4);
  bf_fwd(x[4], x[5], c4, -s4); bf_fwd(x[6], x[7], c4, -s4);
}

// Inverse 3-stage block (stages low->high): (j,j+1) e^{+i4th}; (j,j+2)
// e^{+i2th}/e^{+i(2th+pi/2)}; (j,j+4) e^{+i(th+j pi/4)}.
__device__ __forceinline__ void inv3(float2* x, float c, float s) {
  const float c2 = c * c - s * s, s2 = 2.f * c * s;
  const float c4 = c2 * c2 - s2 * s2, s4 = 2.f * c2 * s2;
  bf_inv(x[0], x[1], c4, s4); bf_inv(x[2], x[3], c4, s4);
  bf_inv(x[4], x[5], c4, s4); bf_inv(x[6], x[7], c4, s4);
  bf_inv(x[0], x[2], c2, s2);  bf_inv(x[4], x[6], c2, s2);
  bf_inv(x[1], x[3], -s2, c2); bf_inv(x[5], x[7], -s2, c2);
  bf_inv(x[0], x[4], c, s);
  { const float cj = RSQ2 * (c - s), sj = RSQ2 * (c + s);
    bf_inv(x[1], x[5], cj, sj); }
  bf_inv(x[2], x[6], -s, c);
  { const float cj = -RSQ2 * (s + c), sj = RSQ2 * (c - s);
    bf_inv(x[3], x[7], cj, sj); }
}

// -------- K1: per-(batch,symbol) FFT, odd-interp real parts -> ws ---------
__global__ __launch_bounds__(256)
void tdi_fft(const float* __restrict__ in_r,
             const float* __restrict__ in_i,
             float* __restrict__ ws) {
  __shared__ __align__(16) float2 As[2176];   // 2048 + pad

  const int u  = threadIdx.x;                 // 0..255
  const int bs = blockIdx.x;                  // b*2 + sym
  // b*4096 + sym*2048 == bs*2048
  const float* __restrict__ pr = in_r + ((size_t)bs << 11);
  const float* __restrict__ pm = in_i + ((size_t)bs << 11);

  float2 x[8];
  float s, c;

  // ---- F1: load + forward stages 10,9,8 (idx = u + 256j), th = u*pi/1024
#pragma unroll
  for (int j = 0; j < 8; ++j)
    x[j] = make_float2(pr[u + 256 * j], pm[u + 256 * j]);
  __sincosf((float)u * (PI_F / 1024.f), &s, &c);
  fwd3(x, c, s);
#pragma unroll
  for (int j = 0; j < 8; ++j) As[pada(u + 256 * j)] = x[j];
  __syncthreads();

  // ---- F2: stages 7,6,5 (idx = (u>>5)*256 + (u&31) + 32j), th = q*pi/128
  {
    const int q = u & 31;
    const int base = ((u >> 5) << 8) | q;
#pragma unroll
    for (int j = 0; j < 8; ++j) x[j] = As[pada(base + 32 * j)];
    __sincosf((float)q * (PI_F / 128.f), &s, &c);
    fwd3(x, c, s);
#pragma unroll
    for (int j = 0; j < 8; ++j) As[pada(base + 32 * j)] = x[j];
  }
  __syncthreads();

  // ---- F3: stages 4,3,2 (idx = (u>>2)*32 + (u&3) + 4j), th = q*pi/16
  {
    const int q = u & 3;
    const int base = ((u >> 2) << 5) | q;
#pragma unroll
    for (int j = 0; j < 8; ++j) x[j] = As[pada(base + 4 * j)];
    __sincosf((float)q * (PI_F / 16.f), &s, &c);
    fwd3(x, c, s);
#pragma unroll
    for (int j = 0; j < 8; ++j) As[pada(base + 4 * j)] = x[j];
  }
  __syncthreads();

  // ---- F4: fwd stages 1,0 + pointwise + inv stages 0,1 (idx = 8u+j) -----
  {
    const int base = u << 3;
#pragma unroll
    for (int j = 0; j < 8; ++j) x[j] = As[pada(base + j)];
    // fwd stage 1: tw=1 for (0,2),(4,6); tw=-i for (1,3),(5,7)
#pragma unroll
    for (int g = 0; g < 8; g += 4) {
      float2 t;
      t.x = x[g].x - x[g+2].x;  t.y = x[g].y - x[g+2].y;
      x[g].x += x[g+2].x;       x[g].y += x[g+2].y;
      x[g+2] = t;
      t.x = x[g+1].x - x[g+3].x; t.y = x[g+1].y - x[g+3].y;
      x[g+1].x += x[g+3].x;      x[g+1].y += x[g+3].y;
      x[g+3] = make_float2(t.y, -t.x);          // * (-i)
    }
    // fwd stage 0: tw=1
#pragma unroll
    for (int g = 0; g < 8; g += 2) {
      float2 t;
      t.x = x[g].x - x[g+1].x; t.y = x[g].y - x[g+1].y;
      x[g].x += x[g+1].x;      x[g].y += x[g+1].y;
      x[g+1] = t;
    }
    // pointwise filter: angle = rev8(u)*pi/2048 + rev3(j)*pi/8,
    // sign = (j odd ? -1 : +1), scale 1/2048
    {
      const float c8[8] = { 1.f,  0.92387953f,  0.70710678f,  0.38268343f,
                            0.f, -0.38268343f, -0.70710678f, -0.92387953f };
      const float s8[8] = { 0.f,  0.38268343f,  0.70710678f,  0.92387953f,
                            1.f,  0.92387953f,  0.70710678f,  0.38268343f };
      float cp, sp;
      __sincosf((float)(__brev((unsigned)u) >> 24) * (PI_F / 2048.f), &sp, &cp);
#pragma unroll
      for (int j = 0; j < 8; ++j) {
        const int rv = ((j & 1) << 2) | (j & 2) | (j >> 2);
        const float sc = (j & 1) ? -(1.f / 2048.f) : (1.f / 2048.f);
        const float fc = (cp * c8[rv] - sp * s8[rv]) * sc;
        const float fs = (sp * c8[rv] + cp * s8[rv]) * sc;
        const float2 a = x[j];
        x[j] = make_float2(a.x * fc - a.y * fs, a.x * fs + a.y * fc);
      }
    }
    // inv stage 0: tw=1
#pragma unroll
    for (int g = 0; g < 8; g += 2) {
      const float2 t = x[g+1];
      x[g+1].x = x[g].x - t.x; x[g+1].y = x[g].y - t.y;
      x[g].x  += t.x;          x[g].y  += t.y;
    }
    // inv stage 1: tw=1 for (0,2),(4,6); tw=+i for (1,3),(5,7)
#pragma unroll
    for (int g = 0; g < 8; g += 4) {
      float2 t = x[g+2];
      x[g+2].x = x[g].x - t.x; x[g+2].y = x[g].y - t.y;
      x[g].x  += t.x;          x[g].y  += t.y;
      t = make_float2(-x[g+3].y, x[g+3].x);     // * (+i)
      x[g+3].x = x[g+1].x - t.x; x[g+3].y = x[g+1].y - t.y;
      x[g+1].x += t.x;           x[g+1].y += t.y;
    }
#pragma unroll
    for (int j = 0; j < 8; ++j) As[pada(base + j)] = x[j];
  }
  __syncthreads();

  // ---- I2: inv stages 2,3,4 (footprint of F3), th = q*pi/16 --------------
  {
    const int q = u & 3;
    const int base = ((u >> 2) << 5) | q;
#pragma unroll
    for (int j = 0; j < 8; ++j) x[j] = As[pada(base + 4 * j)];
    __sincosf((float)q * (PI_F / 16.f), &s, &c);
    inv3(x, c, s);
#pragma unroll
    for (int j = 0; j < 8; ++j) As[pada(base + 4 * j)] = x[j];
  }
  __syncthreads();

  // ---- I3: inv stages 5,6,7 (footprint of F2), th = q*pi/128 -------------
  {
    const int q = u & 31;
    const int base = ((u >> 5) << 8) | q;
#pragma unroll
    for (int j = 0; j < 8; ++j) x[j] = As[pada(base + 32 * j)];
    __sincosf((float)q * (PI_F / 128.f), &s, &c);
    inv3(x, c, s);
#pragma unroll
    for (int j = 0; j < 8; ++j) As[pada(base + 32 * j)] = x[j];
  }
  __syncthreads();

  // ---- I4: inv stages 8,9,10 (idx = u + 256j), th = u*pi/1024 ------------
  // x[j] after inv3 is the final value at index u+256j: store Re() directly
  // from registers (no LDS round-trip, no barrier, no epilogue phase).
  {
#pragma unroll
    for (int j = 0; j < 8; ++j) x[j] = As[pada(u + 256 * j)];
    __sincosf((float)u * (PI_F / 1024.f), &s, &c);
    inv3(x, c, s);
    float* __restrict__ w = ws + ((size_t)bs << 11);
#pragma unroll
    for (int j = 0; j < 8; ++j) w[u + 256 * j] = x[j].x;
  }
}

// -------- K2: streaming lerp + float4 stores (write-BW-bound) -------------
__global__ __launch_bounds__(256)
void tdi_lerp(const float* __restrict__ in_r,
              const float* __restrict__ ws,
              float4* __restrict__ out) {
  const int g = blockIdx.x * 256 + threadIdx.x;   // b*1024 + q
  const int b = g >> 10;
  const int q = g & 1023;

  const float* __restrict__ er = in_r + ((size_t)b << 12);
  const float* __restrict__ wr = ws   + ((size_t)b << 12);
  const float2 E0 = *(const float2*)&er[2 * q];          // even, symbol 0
  const float2 E1 = *(const float2*)&er[2048 + 2 * q];   // even, symbol 1
  const float2 O0 = *(const float2*)&wr[2 * q];          // odd,  symbol 0
  const float2 O1 = *(const float2*)&wr[2048 + 2 * q];   // odd,  symbol 1

  float4* __restrict__ orow = out + (size_t)b * (14 * 1024) + q;
#pragma unroll
  for (int t = 0; t < 14; ++t) {
    const float w = (t < 2) ? 0.f : (t >= 11) ? 1.f : (float)(t - 2) * (1.f / 9.f);
    float4 v;
    v.x = E0.x + w * (E1.x - E0.x);
    v.y = O0.x + w * (O1.x - O0.x);
    v.z = E0.y + w * (E1.y - E0.y);
    v.w = O0.y + w * (O1.y - O0.y);
    orow[(size_t)t * 1024] = v;
  }
}

extern "C" void kernel_launch(void* const* d_in, const int* in_sizes, int n_in,
                              void* d_out, int out_size, void* d_ws, size_t ws_size,
                              hipStream_t stream) {
  const float* hr = (const float*)d_in[0];
  const float* hi = (const float*)d_in[1];
  const int batch = in_sizes[0] / NSC;   // 512 for the reference config
  float* ws = (float*)d_ws;              // needs batch*4096*4 B = 8.4 MB

  tdi_fft<<<dim3(batch * 2), dim3(256), 0, stream>>>(hr, hi, ws);
  tdi_lerp<<<dim3(batch * 4), dim3(256), 0, stream>>>(hr, ws, (float4*)d_out);
}